// Round 5
// baseline (1457.810 us; speedup 1.0000x reference)
//
#include <hip/hip_runtime.h>
#include <stdint.h>

// Problem dims
#define B_ 4096
#define F_ 2048
#define R_ 8
#define O_ 2048
#define N2 (O_ * F_ * R_)   // 33554432  (scores2 / weight2 elements)
#define N1 (R_ * F_)        // 16384     (scores1 / weight1 elements)
#define K2SEL ((uint32_t)(N2 / 2))  // number of mask-1 elements
#define K1SEL ((uint32_t)(N1 / 2))
#define TIE_CAP 8192

// ---------------- workspace layout (uint32 words) ----------------
// w[0]=prefix2 w[1]=K2 w[2]=prefix1 w[3]=K1
// w[4]=tieCount2 w[5]=tieCount1
// w[6..7]=T2 {cutoff_idx, bits}  w[8..9]=T1
// w[64   .. 64+1024)  hist2[4][256]
// w[1088 .. 1088+1024) hist1[4][256]
// w[2112 .. 2112+8192) tie list 2
// w[10304.. 10304+8192) tie list 1
// byte 131072: w1pt (F*R floats), then w1nt (F*R floats)
// byte 262144: Wp (O*F floats = 16MB), then Wn (16MB)

__device__ __forceinline__ uint32_t fkey(float s) {
    return __float_as_uint(fabsf(s));   // monotone for non-negative floats
}

// ---------------- init: zero histograms/counters, set select state -----------
__global__ void init_kernel(uint32_t* w) {
    int t = threadIdx.x;
    for (int i = t; i < 2048; i += 256) w[64 + i] = 0;   // hist2 + hist1
    if (t == 0) {
        w[0] = 0; w[1] = K2SEL;   // scores2 state
        w[2] = 0; w[3] = K1SEL;   // scores1 state
        w[4] = 0; w[5] = 0;       // tie counts
    }
}

// ---------------- radix-select histogram pass --------------------------------
__global__ void hist_kernel(const float* __restrict__ s, int n,
                            const uint32_t* __restrict__ state,
                            uint32_t* __restrict__ hist, int pass) {
    __shared__ uint32_t h[256];
    for (int i = threadIdx.x; i < 256; i += blockDim.x) h[i] = 0;
    __syncthreads();

    uint32_t prefix = state[0];
    int shift_pref = 32 - 8 * pass;   // only used when pass>0
    int shift_bin  = 24 - 8 * pass;

    int stride = gridDim.x * blockDim.x;
    int i0 = blockIdx.x * blockDim.x + threadIdx.x;
    const float4* s4 = reinterpret_cast<const float4*>(s);
    int n4 = n >> 2;
    for (int i = i0; i < n4; i += stride) {
        float4 v = s4[i];
        uint32_t b[4] = { fkey(v.x), fkey(v.y), fkey(v.z), fkey(v.w) };
        if (pass == 0) {
            #pragma unroll
            for (int e = 0; e < 4; ++e) atomicAdd(&h[b[e] >> 24], 1u);
        } else {
            #pragma unroll
            for (int e = 0; e < 4; ++e)
                if ((b[e] >> shift_pref) == prefix)
                    atomicAdd(&h[(b[e] >> shift_bin) & 255u], 1u);
        }
    }
    __syncthreads();
    for (int i = threadIdx.x; i < 256; i += blockDim.x)
        if (h[i]) atomicAdd(&hist[i], h[i]);
}

// ---------------- radix-select bin scan (1 thread) ---------------------------
__global__ void scan_kernel(uint32_t* state, const uint32_t* hist) {
    if (threadIdx.x == 0 && blockIdx.x == 0) {
        uint32_t K = state[1];
        uint32_t prefix = state[0];
        uint32_t cum = 0;
        for (int b = 255; b >= 0; --b) {
            uint32_t hb = hist[b];
            if (cum + hb >= K) {
                state[0] = (prefix << 8) | (uint32_t)b;
                state[1] = K - cum;   // rank (1-based from largest) within bin
                break;
            }
            cum += hb;
        }
    }
}

// ---------------- collect indices of elements equal to threshold bits --------
__global__ void tie_kernel(const float* __restrict__ s, int n,
                           const uint32_t* __restrict__ state,
                           uint32_t* __restrict__ count, uint32_t* __restrict__ list) {
    uint32_t target = state[0];
    int stride = gridDim.x * blockDim.x;
    int i0 = blockIdx.x * blockDim.x + threadIdx.x;
    const float4* s4 = reinterpret_cast<const float4*>(s);
    int n4 = n >> 2;
    for (int i = i0; i < n4; i += stride) {
        float4 v = s4[i];
        uint32_t b[4] = { fkey(v.x), fkey(v.y), fkey(v.z), fkey(v.w) };
        #pragma unroll
        for (int e = 0; e < 4; ++e) {
            if (b[e] == target) {
                uint32_t p = atomicAdd(count, 1u);
                if (p < TIE_CAP) list[p] = (uint32_t)(4 * i + e);
            }
        }
    }
}

// ---------------- find index cutoff among tied elements ----------------------
// cutoff = n1-th largest flat index among tied elements; mask-1 iff idx>=cutoff
__global__ void cutoff_kernel(const uint32_t* __restrict__ count,
                              const uint32_t* __restrict__ list,
                              const uint32_t* __restrict__ state,
                              uint32_t* __restrict__ T, int n) {
    __shared__ uint32_t cnt;
    uint32_t c = *count; if (c > TIE_CAP) c = TIE_CAP;
    uint32_t n1 = state[1];
    uint32_t lo = 0, hi = (uint32_t)(n - 1);
    while (lo < hi) {
        uint32_t mid = lo + (hi - lo + 1) / 2;
        if (threadIdx.x == 0) cnt = 0;
        __syncthreads();
        uint32_t local = 0;
        for (uint32_t i = threadIdx.x; i < c; i += blockDim.x)
            if (list[i] >= mid) local++;
        if (local) atomicAdd(&cnt, local);
        __syncthreads();
        uint32_t cv = cnt;
        __syncthreads();
        if (cv >= n1) lo = mid; else hi = mid - 1;
    }
    if (threadIdx.x == 0) { T[0] = lo; T[1] = state[0]; }
}

// ---------------- build masked, relu-split, transposed w1 --------------------
__global__ void w1t_kernel(const float* __restrict__ w1, const float* __restrict__ s1,
                           const uint32_t* __restrict__ T1,
                           float* __restrict__ w1pt, float* __restrict__ w1nt) {
    int t = blockIdx.x * blockDim.x + threadIdx.x;
    if (t >= N1) return;
    uint32_t tb = T1[1], tc = T1[0];
    int r = t / F_, f = t - r * F_;
    uint32_t kb = fkey(s1[t]);
    bool m = (kb > tb) || (kb == tb && (uint32_t)t >= tc);
    float v = m ? w1[t] : 0.0f;
    w1pt[f * R_ + r] = fmaxf(v, 0.0f);
    w1nt[f * R_ + r] = fminf(v, 0.0f);
}

// ---------------- collapse rank dim: Wp/Wn[o,f] = sum_r w1pm/nm * w2m --------
__global__ void wbuild_kernel(const float* __restrict__ w2, const float* __restrict__ s2,
                              const uint32_t* __restrict__ T2,
                              const float* __restrict__ w1pt, const float* __restrict__ w1nt,
                              float* __restrict__ Wp, float* __restrict__ Wn) {
    int t = blockIdx.x * blockDim.x + threadIdx.x;   // t = o*F_ + f
    int o = t >> 11;
    int f = t & (F_ - 1);
    uint32_t tb = T2[1], tc = T2[0];
    int base = o * (F_ * R_) + f * R_;

    float4 wa = *reinterpret_cast<const float4*>(w2 + base);
    float4 wb = *reinterpret_cast<const float4*>(w2 + base + 4);
    float4 sa = *reinterpret_cast<const float4*>(s2 + base);
    float4 sb = *reinterpret_cast<const float4*>(s2 + base + 4);
    float4 pa = *reinterpret_cast<const float4*>(w1pt + f * R_);
    float4 pb = *reinterpret_cast<const float4*>(w1pt + f * R_ + 4);
    float4 na = *reinterpret_cast<const float4*>(w1nt + f * R_);
    float4 nb = *reinterpret_cast<const float4*>(w1nt + f * R_ + 4);

    float wv[8] = { wa.x, wa.y, wa.z, wa.w, wb.x, wb.y, wb.z, wb.w };
    float sv[8] = { sa.x, sa.y, sa.z, sa.w, sb.x, sb.y, sb.z, sb.w };
    float pv[8] = { pa.x, pa.y, pa.z, pa.w, pb.x, pb.y, pb.z, pb.w };
    float nv[8] = { na.x, na.y, na.z, na.w, nb.x, nb.y, nb.z, nb.w };

    float accp = 0.f, accn = 0.f;
    #pragma unroll
    for (int r = 0; r < 8; ++r) {
        uint32_t kb = fkey(sv[r]);
        bool m = (kb > tb) || (kb == tb && (uint32_t)(base + r) >= tc);
        float wm = m ? wv[r] : 0.0f;
        accp = fmaf(pv[r], wm, accp);
        accn = fmaf(nv[r], wm, accn);
    }
    Wp[t] = accp;
    Wn[t] = accn;
}

// ---------------- fp32 GEMM: out = relu(x)@Wp.T + (-relu(-x))@Wn.T -----------
#define BM 128
#define BN 128
#define BKT 16
__global__ __launch_bounds__(256) void gemm_kernel(const float* __restrict__ x,
                                                   const float* __restrict__ Wp,
                                                   const float* __restrict__ Wn,
                                                   float* __restrict__ out) {
    __shared__ float As[BKT][BM];
    __shared__ float Bp[BKT][BN];
    __shared__ float Bn[BKT][BN];

    int bx = blockIdx.x;           // O tile (16)
    int by = blockIdx.y;           // B tile (32)
    int tid = threadIdx.x;
    int tr = tid >> 4;             // 0..15
    int tc = tid & 15;             // 0..15
    int brow = by * BM, bcol = bx * BN;

    float acc[8][8];
    #pragma unroll
    for (int i = 0; i < 8; ++i)
        #pragma unroll
        for (int j = 0; j < 8; ++j) acc[i][j] = 0.f;

    for (int kt = 0; kt < F_; kt += BKT) {
        #pragma unroll
        for (int hh = 0; hh < 2; ++hh) {
            int qq = tid + hh * 256;       // 0..511 float4 slots of a 128x16 tile
            int row = qq >> 2;             // 0..127
            int c4 = (qq & 3) * 4;         // 0,4,8,12
            float4 av = *reinterpret_cast<const float4*>(x + (size_t)(brow + row) * F_ + kt + c4);
            As[c4 + 0][row] = av.x; As[c4 + 1][row] = av.y;
            As[c4 + 2][row] = av.z; As[c4 + 3][row] = av.w;
            float4 bv = *reinterpret_cast<const float4*>(Wp + (size_t)(bcol + row) * F_ + kt + c4);
            Bp[c4 + 0][row] = bv.x; Bp[c4 + 1][row] = bv.y;
            Bp[c4 + 2][row] = bv.z; Bp[c4 + 3][row] = bv.w;
            float4 cv = *reinterpret_cast<const float4*>(Wn + (size_t)(bcol + row) * F_ + kt + c4);
            Bn[c4 + 0][row] = cv.x; Bn[c4 + 1][row] = cv.y;
            Bn[c4 + 2][row] = cv.z; Bn[c4 + 3][row] = cv.w;
        }
        __syncthreads();

        #pragma unroll
        for (int k = 0; k < BKT; ++k) {
            float a[8], bp[8], bn[8];
            *reinterpret_cast<float4*>(&a[0]) = *reinterpret_cast<float4*>(&As[k][tr * 8]);
            *reinterpret_cast<float4*>(&a[4]) = *reinterpret_cast<float4*>(&As[k][tr * 8 + 4]);
            *reinterpret_cast<float4*>(&bp[0]) = *reinterpret_cast<float4*>(&Bp[k][tc * 8]);
            *reinterpret_cast<float4*>(&bp[4]) = *reinterpret_cast<float4*>(&Bp[k][tc * 8 + 4]);
            *reinterpret_cast<float4*>(&bn[0]) = *reinterpret_cast<float4*>(&Bn[k][tc * 8]);
            *reinterpret_cast<float4*>(&bn[4]) = *reinterpret_cast<float4*>(&Bn[k][tc * 8 + 4]);
            float ap[8], an[8];
            #pragma unroll
            for (int i = 0; i < 8; ++i) { ap[i] = fmaxf(a[i], 0.f); an[i] = fminf(a[i], 0.f); }
            #pragma unroll
            for (int i = 0; i < 8; ++i)
                #pragma unroll
                for (int j = 0; j < 8; ++j)
                    acc[i][j] = fmaf(ap[i], bp[j], fmaf(an[i], bn[j], acc[i][j]));
        }
        __syncthreads();
    }

    #pragma unroll
    for (int i = 0; i < 8; ++i) {
        float4 o0 = { acc[i][0], acc[i][1], acc[i][2], acc[i][3] };
        float4 o1 = { acc[i][4], acc[i][5], acc[i][6], acc[i][7] };
        float* dst = out + (size_t)(brow + tr * 8 + i) * O_ + bcol + tc * 8;
        *reinterpret_cast<float4*>(dst) = o0;
        *reinterpret_cast<float4*>(dst + 4) = o1;
    }
}

extern "C" void kernel_launch(void* const* d_in, const int* in_sizes, int n_in,
                              void* d_out, int out_size, void* d_ws, size_t ws_size,
                              hipStream_t stream) {
    const float* x  = (const float*)d_in[0];
    const float* w1 = (const float*)d_in[1];
    const float* w2 = (const float*)d_in[2];
    const float* s1 = (const float*)d_in[3];
    const float* s2 = (const float*)d_in[4];
    float* out = (float*)d_out;

    uint32_t* w = (uint32_t*)d_ws;
    uint32_t* state2 = w + 0;
    uint32_t* state1 = w + 2;
    uint32_t* cnt2 = w + 4;
    uint32_t* cnt1 = w + 5;
    uint32_t* T2 = w + 6;
    uint32_t* T1 = w + 8;
    uint32_t* hist2 = w + 64;
    uint32_t* hist1 = w + 1088;
    uint32_t* tie2 = w + 2112;
    uint32_t* tie1 = w + 2112 + TIE_CAP;

    float* w1pt = (float*)((char*)d_ws + 131072);
    float* w1nt = w1pt + N1;
    float* Wp = (float*)((char*)d_ws + 262144);
    float* Wn = Wp + (size_t)O_ * F_;

    init_kernel<<<1, 256, 0, stream>>>(w);

    // exact top-half threshold for scores2 (33.5M elements)
    for (int p = 0; p < 4; ++p) {
        hist_kernel<<<2048, 256, 0, stream>>>(s2, N2, state2, hist2 + p * 256, p);
        scan_kernel<<<1, 1, 0, stream>>>(state2, hist2 + p * 256);
    }
    tie_kernel<<<2048, 256, 0, stream>>>(s2, N2, state2, cnt2, tie2);
    cutoff_kernel<<<1, 256, 0, stream>>>(cnt2, tie2, state2, T2, N2);

    // exact top-half threshold for scores1 (16K elements)
    for (int p = 0; p < 4; ++p) {
        hist_kernel<<<64, 256, 0, stream>>>(s1, N1, state1, hist1 + p * 256, p);
        scan_kernel<<<1, 1, 0, stream>>>(state1, hist1 + p * 256);
    }
    tie_kernel<<<64, 256, 0, stream>>>(s1, N1, state1, cnt1, tie1);
    cutoff_kernel<<<1, 256, 0, stream>>>(cnt1, tie1, state1, T1, N1);

    // masked + relu-split + transposed w1  -> w1pt/w1nt [F, R]
    w1t_kernel<<<N1 / 256, 256, 0, stream>>>(w1, s1, T1, w1pt, w1nt);

    // collapse rank dim: Wp/Wn [O, F]
    wbuild_kernel<<<(O_ * F_) / 256, 256, 0, stream>>>(w2, s2, T2, w1pt, w1nt, Wp, Wn);

    // out[B,O] = relu(x) @ Wp.T + min(x,0) @ Wn.T
    gemm_kernel<<<dim3(O_ / BN, B_ / BM), 256, 0, stream>>>(x, Wp, Wn, out);
}

// Round 8
// 886.763 us; speedup vs baseline: 1.6440x; 1.6440x over previous
//
#include <hip/hip_runtime.h>
#include <stdint.h>

// Problem dims
#define B_ 4096
#define F_ 2048
#define R_ 8
#define O_ 2048
#define N2 (O_ * F_ * R_)   // 33554432
#define N1 (R_ * F_)        // 16384
#define K2SEL ((uint32_t)(N2 / 2))
#define K1SEL ((uint32_t)(N1 / 2))
#define TIE_CAP 8192

// ---------------- workspace layout (bytes) ----------------
// 0       : select scratch (uint32 words, as before; < 128 KB)
// 131072  : w1pt (F*R fp32, 64 KB), w1nt (64 KB)
// 262144  : aph/apl/anh/anl  (4 x B_*F_ bf16 = 4 x 16 MB)
// 67371008: bph/bpl/bnh/bnl  (4 x O_*F_ bf16 = 4 x 8 MB)  -> total ~96.3 MB

__device__ __forceinline__ uint32_t fkey(float s) {
    return __float_as_uint(fabsf(s));
}
__device__ __forceinline__ ushort f2bf(float f) {       // RNE fp32->bf16
    uint32_t u = __float_as_uint(f);
    return (ushort)((u + 0x7FFFu + ((u >> 16) & 1u)) >> 16);
}
__device__ __forceinline__ float bf2f(ushort h) {
    return __uint_as_float(((uint32_t)h) << 16);
}

// ---------------- init -------------------------------------------------------
__global__ void init_kernel(uint32_t* w) {
    int t = threadIdx.x;
    for (int i = t; i < 2048; i += 256) w[64 + i] = 0;
    if (t == 0) {
        w[0] = 0; w[1] = K2SEL;
        w[2] = 0; w[3] = K1SEL;
        w[4] = 0; w[5] = 0;
    }
}

// ---------------- radix-select histogram pass (UNCHANGED, verified) ----------
__global__ void hist_kernel(const float* __restrict__ s, int n,
                            const uint32_t* __restrict__ state,
                            uint32_t* __restrict__ hist, int pass) {
    __shared__ uint32_t h[256];
    for (int i = threadIdx.x; i < 256; i += blockDim.x) h[i] = 0;
    __syncthreads();

    uint32_t prefix = state[0];
    int shift_pref = 32 - 8 * pass;
    int shift_bin  = 24 - 8 * pass;

    int stride = gridDim.x * blockDim.x;
    int i0 = blockIdx.x * blockDim.x + threadIdx.x;
    const float4* s4 = reinterpret_cast<const float4*>(s);
    int n4 = n >> 2;
    for (int i = i0; i < n4; i += stride) {
        float4 v = s4[i];
        uint32_t b[4] = { fkey(v.x), fkey(v.y), fkey(v.z), fkey(v.w) };
        if (pass == 0) {
            #pragma unroll
            for (int e = 0; e < 4; ++e) atomicAdd(&h[b[e] >> 24], 1u);
        } else {
            #pragma unroll
            for (int e = 0; e < 4; ++e)
                if ((b[e] >> shift_pref) == prefix)
                    atomicAdd(&h[(b[e] >> shift_bin) & 255u], 1u);
        }
    }
    __syncthreads();
    for (int i = threadIdx.x; i < 256; i += blockDim.x)
        if (h[i]) atomicAdd(&hist[i], h[i]);
}

__global__ void scan_kernel(uint32_t* state, const uint32_t* hist) {
    if (threadIdx.x == 0 && blockIdx.x == 0) {
        uint32_t K = state[1];
        uint32_t prefix = state[0];
        uint32_t cum = 0;
        for (int b = 255; b >= 0; --b) {
            uint32_t hb = hist[b];
            if (cum + hb >= K) {
                state[0] = (prefix << 8) | (uint32_t)b;
                state[1] = K - cum;
                break;
            }
            cum += hb;
        }
    }
}

__global__ void tie_kernel(const float* __restrict__ s, int n,
                           const uint32_t* __restrict__ state,
                           uint32_t* __restrict__ count, uint32_t* __restrict__ list) {
    uint32_t target = state[0];
    int stride = gridDim.x * blockDim.x;
    int i0 = blockIdx.x * blockDim.x + threadIdx.x;
    const float4* s4 = reinterpret_cast<const float4*>(s);
    int n4 = n >> 2;
    for (int i = i0; i < n4; i += stride) {
        float4 v = s4[i];
        uint32_t b[4] = { fkey(v.x), fkey(v.y), fkey(v.z), fkey(v.w) };
        #pragma unroll
        for (int e = 0; e < 4; ++e) {
            if (b[e] == target) {
                uint32_t p = atomicAdd(count, 1u);
                if (p < TIE_CAP) list[p] = (uint32_t)(4 * i + e);
            }
        }
    }
}

__global__ void cutoff_kernel(const uint32_t* __restrict__ count,
                              const uint32_t* __restrict__ list,
                              const uint32_t* __restrict__ state,
                              uint32_t* __restrict__ T, int n) {
    __shared__ uint32_t cnt;
    uint32_t c = *count; if (c > TIE_CAP) c = TIE_CAP;
    uint32_t n1 = state[1];
    uint32_t lo = 0, hi = (uint32_t)(n - 1);
    while (lo < hi) {
        uint32_t mid = lo + (hi - lo + 1) / 2;
        if (threadIdx.x == 0) cnt = 0;
        __syncthreads();
        uint32_t local = 0;
        for (uint32_t i = threadIdx.x; i < c; i += blockDim.x)
            if (list[i] >= mid) local++;
        if (local) atomicAdd(&cnt, local);
        __syncthreads();
        uint32_t cv = cnt;
        __syncthreads();
        if (cv >= n1) lo = mid; else hi = mid - 1;
    }
    if (threadIdx.x == 0) { T[0] = lo; T[1] = state[0]; }
}

// ---------------- masked, relu-split, transposed w1 (fp32, small) ------------
__global__ void w1t_kernel(const float* __restrict__ w1, const float* __restrict__ s1,
                           const uint32_t* __restrict__ T1,
                           float* __restrict__ w1pt, float* __restrict__ w1nt) {
    int t = blockIdx.x * blockDim.x + threadIdx.x;
    if (t >= N1) return;
    uint32_t tb = T1[1], tc = T1[0];
    int r = t / F_, f = t - r * F_;
    uint32_t kb = fkey(s1[t]);
    bool m = (kb > tb) || (kb == tb && (uint32_t)t >= tc);
    float v = m ? w1[t] : 0.0f;
    w1pt[f * R_ + r] = fmaxf(v, 0.0f);
    w1nt[f * R_ + r] = fminf(v, 0.0f);
}

// ---------------- split x into relu-parts, bf16 hi/lo ------------------------
__global__ void xsplit_kernel(const float* __restrict__ x,
                              ushort* __restrict__ ph, ushort* __restrict__ pl,
                              ushort* __restrict__ nh, ushort* __restrict__ nl) {
    int t = blockIdx.x * blockDim.x + threadIdx.x;   // one float4
    float4 v = reinterpret_cast<const float4*>(x)[t];
    float vv[4] = { v.x, v.y, v.z, v.w };
    ushort oph[4], opl[4], onh[4], onl[4];
    #pragma unroll
    for (int e = 0; e < 4; ++e) {
        float p = fmaxf(vv[e], 0.f), n = fminf(vv[e], 0.f);
        ushort h1 = f2bf(p); oph[e] = h1; opl[e] = f2bf(p - bf2f(h1));
        ushort h2 = f2bf(n); onh[e] = h2; onl[e] = f2bf(n - bf2f(h2));
    }
    *reinterpret_cast<ushort4*>(&ph[t * 4]) = make_ushort4(oph[0], oph[1], oph[2], oph[3]);
    *reinterpret_cast<ushort4*>(&pl[t * 4]) = make_ushort4(opl[0], opl[1], opl[2], opl[3]);
    *reinterpret_cast<ushort4*>(&nh[t * 4]) = make_ushort4(onh[0], onh[1], onh[2], onh[3]);
    *reinterpret_cast<ushort4*>(&nl[t * 4]) = make_ushort4(onl[0], onl[1], onl[2], onl[3]);
}

// ---------------- rank-collapse: Wp/Wn[o,f], output bf16 hi/lo ---------------
__global__ void wbuild_kernel(const float* __restrict__ w2, const float* __restrict__ s2,
                              const uint32_t* __restrict__ T2,
                              const float* __restrict__ w1pt, const float* __restrict__ w1nt,
                              ushort* __restrict__ bph, ushort* __restrict__ bpl,
                              ushort* __restrict__ bnh, ushort* __restrict__ bnl) {
    int t = blockIdx.x * blockDim.x + threadIdx.x;   // t = o*F_ + f
    int f = t & (F_ - 1);
    uint32_t tb = T2[1], tc = T2[0];
    int base = (t >> 11) * (F_ * R_) + f * R_;

    float4 wa = *reinterpret_cast<const float4*>(w2 + base);
    float4 wb = *reinterpret_cast<const float4*>(w2 + base + 4);
    float4 sa = *reinterpret_cast<const float4*>(s2 + base);
    float4 sb = *reinterpret_cast<const float4*>(s2 + base + 4);
    float4 pa = *reinterpret_cast<const float4*>(w1pt + f * R_);
    float4 pb = *reinterpret_cast<const float4*>(w1pt + f * R_ + 4);
    float4 na = *reinterpret_cast<const float4*>(w1nt + f * R_);
    float4 nb = *reinterpret_cast<const float4*>(w1nt + f * R_ + 4);

    float wv[8] = { wa.x, wa.y, wa.z, wa.w, wb.x, wb.y, wb.z, wb.w };
    float sv[8] = { sa.x, sa.y, sa.z, sa.w, sb.x, sb.y, sb.z, sb.w };
    float pv[8] = { pa.x, pa.y, pa.z, pa.w, pb.x, pb.y, pb.z, pb.w };
    float nv[8] = { na.x, na.y, na.z, na.w, nb.x, nb.y, nb.z, nb.w };

    float accp = 0.f, accn = 0.f;
    #pragma unroll
    for (int r = 0; r < 8; ++r) {
        uint32_t kb = fkey(sv[r]);
        bool m = (kb > tb) || (kb == tb && (uint32_t)(base + r) >= tc);
        float wm = m ? wv[r] : 0.0f;
        accp = fmaf(pv[r], wm, accp);
        accn = fmaf(nv[r], wm, accn);
    }
    ushort h1 = f2bf(accp); bph[t] = h1; bpl[t] = f2bf(accp - bf2f(h1));
    ushort h2 = f2bf(accn); bnh[t] = h2; bnl[t] = f2bf(accn - bf2f(h2));
}

// ---------------- split-bf16 MFMA GEMM (m97 structure) -----------------------
// out[B,O] = sum_plane  Aplane @ Wplane.T   with  A*B ~ Ah*Bh + Ah*Bl + Al*Bh
typedef __attribute__((ext_vector_type(8))) short bf16x8;
typedef __attribute__((ext_vector_type(4))) float f32x4;

__device__ __forceinline__ void gload16(const void* g, void* l) {
    __builtin_amdgcn_global_load_lds((const __attribute__((address_space(1))) void*)g,
                                     (__attribute__((address_space(3))) void*)l, 16, 0, 0);
}

__global__ __launch_bounds__(256) void mfma_gemm(
    const ushort* __restrict__ aph, const ushort* __restrict__ apl,
    const ushort* __restrict__ anh, const ushort* __restrict__ anl,
    const ushort* __restrict__ bph, const ushort* __restrict__ bpl,
    const ushort* __restrict__ bnh, const ushort* __restrict__ bnl,
    float* __restrict__ out) {
    // LDS: 4 tiles [128 rows][32 k] bf16: 0=A_hi 1=A_lo 2=B_hi 3=B_lo (32 KB)
    __shared__ ushort lds[4][128][32];

    const int tid  = threadIdx.x;
    const int wid  = tid >> 6;          // wave 0..3 (stages tile wid)
    const int lane = tid & 63;
    const int brow = blockIdx.y * 128;
    const int bcol = blockIdx.x * 128;
    const int wr = (wid >> 1) * 64;     // wave's 64x64 output corner
    const int wc = (wid & 1) * 64;

    f32x4 acc[4][4] = {};

    // staging geometry: wave stages its tile as 8 segments of 1 KB
    // lane covers (row = t*16 + lane/4, kchunk = lane%4) -> 16B
    const int srow = lane >> 2;
    const int scol = (lane & 3) * 8;

    #pragma unroll 1
    for (int plane = 0; plane < 2; ++plane) {
        const ushort* tsrc =
            (wid == 0) ? (plane ? anh : aph) :
            (wid == 1) ? (plane ? anl : apl) :
            (wid == 2) ? (plane ? bnh : bph) :
                         (plane ? bnl : bpl);
        const int rowbase = (wid < 2) ? brow : bcol;

        #pragma unroll 1
        for (int k0 = 0; k0 < F_; k0 += 32) {
            // ---- stage 32 KB via global_load_lds (lane offset implicit) ----
            #pragma unroll
            for (int t = 0; t < 8; ++t) {
                const ushort* g = tsrc + (size_t)(rowbase + t * 16 + srow) * F_ + k0 + scol;
                gload16(g, (void*)&lds[wid][t * 16][0]);
            }
            __syncthreads();

            // ---- fragments ----
            bf16x8 ah[4], al[4], bh[4], bl[4];
            const int fr = lane & 15;
            const int kc = (lane >> 4) * 8;
            #pragma unroll
            for (int i = 0; i < 4; ++i) {
                ah[i] = *(const bf16x8*)&lds[0][wr + i * 16 + fr][kc];
                al[i] = *(const bf16x8*)&lds[1][wr + i * 16 + fr][kc];
                bh[i] = *(const bf16x8*)&lds[2][wc + i * 16 + fr][kc];
                bl[i] = *(const bf16x8*)&lds[3][wc + i * 16 + fr][kc];
            }
            // ---- 48 MFMAs: hi*hi + hi*lo + lo*hi ----
            #pragma unroll
            for (int i = 0; i < 4; ++i)
                #pragma unroll
                for (int j = 0; j < 4; ++j) {
                    acc[i][j] = __builtin_amdgcn_mfma_f32_16x16x32_bf16(ah[i], bh[j], acc[i][j], 0, 0, 0);
                    acc[i][j] = __builtin_amdgcn_mfma_f32_16x16x32_bf16(ah[i], bl[j], acc[i][j], 0, 0, 0);
                    acc[i][j] = __builtin_amdgcn_mfma_f32_16x16x32_bf16(al[i], bh[j], acc[i][j], 0, 0, 0);
                }
            __syncthreads();
        }
    }

    // ---- epilogue: C/D layout col=lane&15, row=(lane>>4)*4+q (m89/m91) ----
    #pragma unroll
    for (int i = 0; i < 4; ++i) {
        int orow0 = brow + wr + i * 16 + (lane >> 4) * 4;
        #pragma unroll
        for (int j = 0; j < 4; ++j) {
            int ocol = bcol + wc + j * 16 + (lane & 15);
            #pragma unroll
            for (int q = 0; q < 4; ++q)
                out[(size_t)(orow0 + q) * O_ + ocol] = acc[i][j][q];
        }
    }
}

extern "C" void kernel_launch(void* const* d_in, const int* in_sizes, int n_in,
                              void* d_out, int out_size, void* d_ws, size_t ws_size,
                              hipStream_t stream) {
    const float* x  = (const float*)d_in[0];
    const float* w1 = (const float*)d_in[1];
    const float* w2 = (const float*)d_in[2];
    const float* s1 = (const float*)d_in[3];
    const float* s2 = (const float*)d_in[4];
    float* out = (float*)d_out;

    uint32_t* w = (uint32_t*)d_ws;
    uint32_t* state2 = w + 0;
    uint32_t* state1 = w + 2;
    uint32_t* cnt2 = w + 4;
    uint32_t* cnt1 = w + 5;
    uint32_t* T2 = w + 6;
    uint32_t* T1 = w + 8;
    uint32_t* hist2 = w + 64;
    uint32_t* hist1 = w + 1088;
    uint32_t* tie2 = w + 2112;
    uint32_t* tie1 = w + 2112 + TIE_CAP;

    float* w1pt = (float*)((char*)d_ws + 131072);
    float* w1nt = w1pt + N1;

    char* base = (char*)d_ws + 262144;
    ushort* aph = (ushort*)(base);
    ushort* apl = aph + (size_t)B_ * F_;
    ushort* anh = apl + (size_t)B_ * F_;
    ushort* anl = anh + (size_t)B_ * F_;
    ushort* bph = anl + (size_t)B_ * F_;
    ushort* bpl = bph + (size_t)O_ * F_;
    ushort* bnh = bpl + (size_t)O_ * F_;
    ushort* bnl = bnh + (size_t)O_ * F_;

    init_kernel<<<1, 256, 0, stream>>>(w);

    // x split (independent of selection)
    xsplit_kernel<<<(B_ * F_ / 4) / 256, 256, 0, stream>>>(x, aph, apl, anh, anl);

    // exact top-half threshold for scores2
    for (int p = 0; p < 4; ++p) {
        hist_kernel<<<2048, 256, 0, stream>>>(s2, N2, state2, hist2 + p * 256, p);
        scan_kernel<<<1, 1, 0, stream>>>(state2, hist2 + p * 256);
    }
    tie_kernel<<<2048, 256, 0, stream>>>(s2, N2, state2, cnt2, tie2);
    cutoff_kernel<<<1, 256, 0, stream>>>(cnt2, tie2, state2, T2, N2);

    // exact top-half threshold for scores1
    for (int p = 0; p < 4; ++p) {
        hist_kernel<<<64, 256, 0, stream>>>(s1, N1, state1, hist1 + p * 256, p);
        scan_kernel<<<1, 1, 0, stream>>>(state1, hist1 + p * 256);
    }
    tie_kernel<<<64, 256, 0, stream>>>(s1, N1, state1, cnt1, tie1);
    cutoff_kernel<<<1, 256, 0, stream>>>(cnt1, tie1, state1, T1, N1);

    // masked + relu-split + transposed w1
    w1t_kernel<<<N1 / 256, 256, 0, stream>>>(w1, s1, T1, w1pt, w1nt);

    // rank-collapse -> bf16 hi/lo weight planes
    wbuild_kernel<<<(O_ * F_) / 256, 256, 0, stream>>>(w2, s2, T2, w1pt, w1nt,
                                                       bph, bpl, bnh, bnl);

    // split-bf16 MFMA GEMM
    mfma_gemm<<<dim3(O_ / 128, B_ / 128), 256, 0, stream>>>(
        aph, apl, anh, anl, bph, bpl, bnh, bnl, out);
}